// Round 7
// baseline (191.646 us; speedup 1.0000x reference)
//
#include <hip/hip_runtime.h>

// Batch_Edge: B=512 graphs x 256 nodes; out1=tanh([h|emb[g]]@W1+b1);
// out2=tanh(out1@W2+b2); edges=out2@W3+b3 -> out[2*node+e].
// ebias trick: layer-1 K=128 (h@W1[:128]), emb folded into per-graph ebias.
// R7: 1 blk/graph, 4 waves, 64-row tiles, acc[4][4]: 66us, Occ 19%, no spill.
// R8-R11: more blocks at lb(,3/4) with 64-row tiles -> always spills
//   (acc 64 + arch ~100 > budget). R12: 32-row tiles, acc[2][4]: spill ~gone
//   (WRITE 8.8MB, arch 84 + acc 32 = 116), Occ 29%, but 95us -- small tiles
//   double barriers/B-frag-refetch/preamble: tile economics beat occupancy.
// R13 synthesis: 64-row tiles AND acc[2][4]: 512-thr blocks, 8 waves =
//   2 row-halves x 4 col-quarters (32 rows x 64 cols per wave). Grid 512,
//   1 blk/graph, preamble once, lb(512,2) -> 2 blk/CU = 4 waves/SIMD (50%).
//   Budget 512/4=128 >= R12-measured demand ~116. R7 economics + 2x waves.
// ws: W1P 64K + W2P 128K = 196608 <= 262208 (R4-proven bound).

typedef __attribute__((ext_vector_type(8))) short s16x8;  // 8 bf16 = 4 VGPRs
typedef __attribute__((ext_vector_type(4))) float f32x4;

#define K2   256
#define KH   128
#define LDK  264    // row stride (elems): 528B rows, 16B-aligned

__device__ __forceinline__ float b2f(unsigned short u) {
  return __builtin_bit_cast(float, (unsigned int)u << 16);
}
__device__ __forceinline__ unsigned short f2b(float f) {
  unsigned int u = __builtin_bit_cast(unsigned int, f);
  u += 0x7fffu + ((u >> 16) & 1u);   // RNE
  return (unsigned short)(u >> 16);
}
// tanh via Pade(5/4)+clamp: max err ~1.1e-3 (< bf16 quantum), no NaN/ovf.
__device__ __forceinline__ float pade_tanh(float x) {
  float x2 = x * x;
  float x4 = x2 * x2;
  float num = x * (945.0f + 105.0f * x2 + x4);
  float den = __builtin_fmaf(15.0f, x4, __builtin_fmaf(420.0f, x2, 945.0f));
  float r = num * __builtin_amdgcn_rcpf(den);
  return __builtin_fmaxf(-1.0f, __builtin_fminf(1.0f, r));
}
// dtype probe: low u16 of each W_embed dword has bf16-plausible exponent iff
// storage is bf16 (values ~N(0,1/sqrt(128))).
__device__ __forceinline__ unsigned int probe_is16(const unsigned int* wraw,
                                                   int t) {
  unsigned int w = wraw[t];
  unsigned int e = (w >> 7) & 0xFFu;
  unsigned long long m = __ballot(e >= 96 && e < 128);
  return (__popcll(m) >= 32) ? 1u : 0u;
}

// ---- prep: frag-pack W1[:128] and W2 ----
// pack: D[(n>>4)*pk + (k>>3)*128 + (n&15)*8 + (k&7)]; B-frag load for
// (nblk,kchunk) is one contiguous 1KB wave read. (Verified R5/R6.)
__global__ __launch_bounds__(256) void prep_pack(
    const void* __restrict__ W1, const void* __restrict__ W2,
    const void* __restrict__ Wemb,
    unsigned short* __restrict__ W1P, unsigned short* __restrict__ W2P)
{
  __shared__ unsigned int flagLds;
  const int blk = blockIdx.x, t = threadIdx.x;
  if (t < 64) { unsigned int f = probe_is16((const unsigned int*)Wemb, t);
                if (t == 0) flagLds = f; }
  __syncthreads();
  const bool is16 = flagLds != 0u;

  const void* S; unsigned short* D; int k0, n0, pk;
  if (blk < 32) { S = W1; D = W1P; pk = 2048;                  // 128k x 256n
                  k0 = (blk & 3) * 32; n0 = (blk >> 2) * 32; }
  else { int b = blk - 32; S = W2; D = W2P; pk = 4096;         // 256k x 256n
         k0 = (b & 7) * 32; n0 = (b >> 3) * 32; }
  #pragma unroll
  for (int q = 0; q < 4; ++q) {
    int idx = t + 256 * q;                 // 32k x 32n, n fast (coalesced)
    int ln = idx & 31, lk = idx >> 5;
    int n = n0 + ln, k = k0 + lk;
    unsigned short v = is16
        ? ((const unsigned short*)S)[k * K2 + n]
        : f2b(((const float*)S)[k * K2 + n]);
    D[(n >> 4) * pk + (k >> 3) * 128 + (n & 15) * 8 + (k & 7)] = v;
  }
}

// ---- fused MLP: 1 block/graph; 4 tiles x 64 rows; 512 thr = 8 waves ------
// wave (wrh = w>>2, wc = w&3) owns rows [32*wrh, 32*wrh+32) x cols
// [64*wc, 64*wc+64) of each tile: acc[2][4] = 32 AGPR per wave.
__global__ __launch_bounds__(512, 2) void mlp_graph(
    const void* __restrict__ h,     const void* __restrict__ last,
    const void* __restrict__ Wemb,  const void* __restrict__ bemb,
    const void* __restrict__ W1,    const void* __restrict__ b1,
    const void* __restrict__ b2,
    const void* __restrict__ W3,    const void* __restrict__ b3,
    const unsigned short* __restrict__ W1P,
    const unsigned short* __restrict__ W2P,
    void* __restrict__ out)
{
  __shared__ __align__(16) unsigned short smA[64 * LDK];  // h / out1 / out2
  __shared__ float embp[4][KH];                // embf K-quarter partials
  __shared__ float emb32[KH];                  // emb row, f32
  __shared__ float ebias[K2];
  __shared__ float headp[4][64][2];
  __shared__ unsigned int flagLds;

  const int t    = threadIdx.x;
  const int lane = t & 63, w = t >> 6;         // 8 waves
  const int wc   = w & 3;                      // col-quarter [64wc, 64wc+64)
  const int wrh  = w >> 2;                     // row-half [32wrh, 32wrh+32)
  const int quad = lane >> 4, l16 = lane & 15;
  const int g    = blockIdx.x;                 // graph id

  if (t < 64) { unsigned int f = probe_is16((const unsigned int*)Wemb, t);
                if (t == 0) flagLds = f; }
  __syncthreads();
  const bool is16 = flagLds != 0u;

  // ---- embf partials: all 512 thr; col j=t&127, K-quarter=t>>7 ----
  {
    const int j = t & 127, qtr = t >> 7, k0 = qtr * 32;
    float a0 = 0.f, a1 = 0.f, a2 = 0.f, a3 = 0.f;
    if (is16) {
      const unsigned short* lp = (const unsigned short*)last + g * KH;
      const unsigned short* wp = (const unsigned short*)Wemb;
      #pragma unroll 4
      for (int k = k0; k < k0 + 32; k += 4) {
        a0 += b2f(lp[k])     * b2f(wp[k * KH + j]);
        a1 += b2f(lp[k + 1]) * b2f(wp[(k + 1) * KH + j]);
        a2 += b2f(lp[k + 2]) * b2f(wp[(k + 2) * KH + j]);
        a3 += b2f(lp[k + 3]) * b2f(wp[(k + 3) * KH + j]);
      }
    } else {
      const float* lp = (const float*)last + g * KH;
      const float* wp = (const float*)Wemb;
      #pragma unroll 4
      for (int k = k0; k < k0 + 32; k += 4) {
        a0 += lp[k]     * wp[k * KH + j];
        a1 += lp[k + 1] * wp[(k + 1) * KH + j];
        a2 += lp[k + 2] * wp[(k + 2) * KH + j];
        a3 += lp[k + 3] * wp[(k + 3) * KH + j];
      }
    }
    embp[qtr][j] = (a0 + a1) + (a2 + a3);
  }

  // ---- persistent per-wave registers: head W3 frags, biases ----
  s16x8 bh[2];                                 // head B: wc covers k 64wc..
  #pragma unroll
  for (int s = 0; s < 2; ++s) {
    int kk = 2 * wc + s;
    #pragma unroll
    for (int j = 0; j < 8; ++j) {
      int kidx = (kk * 32 + quad * 8 + j) * 2 + (l16 & 1);
      bh[s][j] = is16 ? (short)((const unsigned short*)W3)[kidx]
                      : (short)f2b(((const float*)W3)[kidx]);
    }
  }
  float b2v[4];
  #pragma unroll
  for (int c = 0; c < 4; ++c) {
    int col = wc * 64 + c * 16 + l16;
    b2v[c] = is16 ? b2f(((const unsigned short*)b2)[col])
                  : ((const float*)b2)[col];
  }
  float b3e = 0.f;
  if (t < 128)
    b3e = is16 ? b2f(((const unsigned short*)b3)[t & 1])
               : ((const float*)b3)[t & 1];
  __syncthreads();                             // embp ready

  if (t < KH) {
    float e = is16 ? b2f(((const unsigned short*)bemb)[t])
                   : ((const float*)bemb)[t];
    emb32[t] = e + embp[0][t] + embp[1][t] + embp[2][t] + embp[3][t];
  }
  __syncthreads();                             // emb32 ready

  // ---- ebias[col=t] = b1[col] + sum_k emb32[k]*W1[128+k][col] (f32 GEMV) --
  // t<256 only (once per graph); L2-hot raw W1 rows 128:255 (proven R11).
  if (t < K2) {
    float s = is16 ? b2f(((const unsigned short*)b1)[t])
                   : ((const float*)b1)[t];
    if (is16) {
      const unsigned short* wp = (const unsigned short*)W1
                                 + (size_t)KH * K2 + t;
      #pragma unroll 4
      for (int k = 0; k < KH; ++k)
        s = __builtin_fmaf(emb32[k], b2f(wp[(size_t)k * K2]), s);
    } else {
      const float* wp = (const float*)W1 + (size_t)KH * K2 + t;
      #pragma unroll 4
      for (int k = 0; k < KH; ++k)
        s = __builtin_fmaf(emb32[k], wp[(size_t)k * K2], s);
    }
    ebias[t] = s;
  }

  // ---- prefetch tile 0 h into registers (64 rows x 16 chunks / 512 thr) --
  uint4 hreg[2];
  const int pr = t >> 4, pc = t & 15;          // rows pr, pr+32; chunk pc
  auto load_tile = [&](int tile) {
    int rbase = g * 256 + tile * 64;
    if (is16) {
      const uint4* hp = (const uint4*)h;
      #pragma unroll
      for (int i = 0; i < 2; ++i)
        hreg[i] = hp[(size_t)(rbase + pr + 32 * i) * 16 + pc];
    } else {
      const float4* hf = (const float4*)h;
      #pragma unroll
      for (int i = 0; i < 2; ++i) {
        float4 va = hf[(size_t)(rbase + pr + 32 * i) * 32 + pc * 2];
        float4 vb = hf[(size_t)(rbase + pr + 32 * i) * 32 + pc * 2 + 1];
        ushort4 ua, ub;
        ua.x = f2b(va.x); ua.y = f2b(va.y); ua.z = f2b(va.z); ua.w = f2b(va.w);
        ub.x = f2b(vb.x); ub.y = f2b(vb.y); ub.z = f2b(vb.z); ub.w = f2b(vb.w);
        hreg[i] = make_uint4(
            (unsigned)ua.x | ((unsigned)ua.y << 16),
            (unsigned)ua.z | ((unsigned)ua.w << 16),
            (unsigned)ub.x | ((unsigned)ub.y << 16),
            (unsigned)ub.z | ((unsigned)ub.w << 16));
      }
    }
  };
  load_tile(0);

  f32x4 acc[2][4];                             // 32 AGPR (R12-proven size)
  for (int tile = 0; tile < 4; ++tile) {
    const int base = g * 256 + tile * 64;
    __syncthreads();                           // prev tile fully consumed
    #pragma unroll
    for (int i = 0; i < 2; ++i)
      *(uint4*)&smA[(pr + 32 * i) * LDK + pc * 8] = hreg[i];
    if (tile < 3) load_tile(tile + 1);         // overlap HBM with compute
    __syncthreads();                           // h tile visible

    // ---- layer 1: K=128, B streamed from W1P (L2-hot) ----
    #pragma unroll
    for (int i = 0; i < 2; ++i)
      #pragma unroll
      for (int c = 0; c < 4; ++c) acc[i][c] = f32x4{0.f, 0.f, 0.f, 0.f};
    #pragma unroll
    for (int kk = 0; kk < 4; ++kk) {
      s16x8 a[2], b[4];
      #pragma unroll
      for (int i = 0; i < 2; ++i)
        a[i] = *(const s16x8*)&smA[(wrh * 32 + i * 16 + l16) * LDK
                                   + kk * 32 + quad * 8];
      #pragma unroll
      for (int c = 0; c < 4; ++c)
        b[c] = *(const s16x8*)&W1P[(wc * 4 + c) * 2048
                                   + (kk * 4 + quad) * 128 + l16 * 8];
      #pragma unroll
      for (int i = 0; i < 2; ++i)
        #pragma unroll
        for (int c = 0; c < 4; ++c)
          acc[i][c] = __builtin_amdgcn_mfma_f32_16x16x32_bf16(
              a[i], b[c], acc[i][c], 0, 0, 0);
    }
    __syncthreads();                           // A reads done before overwrite
    #pragma unroll
    for (int c = 0; c < 4; ++c) {
      int col = wc * 64 + c * 16 + l16;
      float eb = ebias[col];
      #pragma unroll
      for (int i = 0; i < 2; ++i)
        #pragma unroll
        for (int rg = 0; rg < 4; ++rg)         // D: row=quad*4+rg, col=l16
          smA[(wrh * 32 + i * 16 + quad * 4 + rg) * LDK + col] =
              f2b(pade_tanh(acc[i][c][rg] + eb));
    }
    __syncthreads();

    // ---- layer 2: K=256, B from W2P (L2-hot) ----
    #pragma unroll
    for (int i = 0; i < 2; ++i)
      #pragma unroll
      for (int c = 0; c < 4; ++c) acc[i][c] = f32x4{0.f, 0.f, 0.f, 0.f};
    #pragma unroll 2
    for (int kk = 0; kk < 8; ++kk) {
      s16x8 a[2], b[4];
      #pragma unroll
      for (int i = 0; i < 2; ++i)
        a[i] = *(const s16x8*)&smA[(wrh * 32 + i * 16 + l16) * LDK
                                   + kk * 32 + quad * 8];
      #pragma unroll
      for (int c = 0; c < 4; ++c)
        b[c] = *(const s16x8*)&W2P[(wc * 4 + c) * 4096
                                   + (kk * 4 + quad) * 128 + l16 * 8];
      #pragma unroll
      for (int i = 0; i < 2; ++i)
        #pragma unroll
        for (int c = 0; c < 4; ++c)
          acc[i][c] = __builtin_amdgcn_mfma_f32_16x16x32_bf16(
              a[i], b[c], acc[i][c], 0, 0, 0);
    }
    __syncthreads();
    #pragma unroll
    for (int c = 0; c < 4; ++c) {
      int col = wc * 64 + c * 16 + l16;
      #pragma unroll
      for (int i = 0; i < 2; ++i)
        #pragma unroll
        for (int rg = 0; rg < 4; ++rg)
          smA[(wrh * 32 + i * 16 + quad * 4 + rg) * LDK + col] =
              f2b(pade_tanh(acc[i][c][rg] + b2v[c]));
    }
    __syncthreads();

    // ---- head via MFMA: wave-col wc covers k in [64wc, 64wc+64) ----
    // accumulates into acc[i][0] (dead after layer-2 epilogue): forced reuse.
    {
      #pragma unroll
      for (int i = 0; i < 2; ++i) acc[i][0] = f32x4{0.f, 0.f, 0.f, 0.f};
      #pragma unroll
      for (int s = 0; s < 2; ++s) {
        int kk = 2 * wc + s;
        #pragma unroll
        for (int i = 0; i < 2; ++i) {
          s16x8 a = *(const s16x8*)&smA[(wrh * 32 + i * 16 + l16) * LDK
                                        + kk * 32 + quad * 8];
          acc[i][0] = __builtin_amdgcn_mfma_f32_16x16x32_bf16(
              a, bh[s], acc[i][0], 0, 0, 0);
        }
      }
      if (l16 < 2) {
        #pragma unroll
        for (int i = 0; i < 2; ++i)
          #pragma unroll
          for (int rg = 0; rg < 4; ++rg)
            headp[wc][wrh * 32 + i * 16 + quad * 4 + rg][l16] =
                acc[i][0][rg];
      }
    }
    __syncthreads();
    if (t < 128) {
      const int r = t >> 1, e = t & 1;
      float s = b3e + headp[0][r][e] + headp[1][r][e]
                    + headp[2][r][e] + headp[3][r][e];
      size_t idx = (size_t)(base + r) * 2 + e;
      if (is16) ((unsigned short*)out)[idx] = f2b(s);
      else      ((float*)out)[idx] = s;
    }
  }
}

extern "C" void kernel_launch(void* const* d_in, const int* in_sizes, int n_in,
                              void* d_out, int out_size, void* d_ws, size_t ws_size,
                              hipStream_t stream) {
  (void)in_sizes; (void)n_in; (void)out_size; (void)ws_size;
  const void* last = d_in[0];
  const void* h    = d_in[1];
  const void* Wemb = d_in[2];
  const void* bemb = d_in[3];
  const void* W1   = d_in[4];
  const void* b1   = d_in[5];
  const void* W2   = d_in[6];
  const void* b2   = d_in[7];
  const void* W3   = d_in[8];
  const void* b3   = d_in[9];
  // d_in[10]=segment_ids, d_in[11]=max_nodes: regular structure, unused.

  // ws usage: 196608 B <= 262208 (R4-proven bound).
  char* ws = (char*)d_ws;
  unsigned short* W1P   = (unsigned short*)(ws);            // 64 KB
  unsigned short* W2P   = (unsigned short*)(ws + 65536);    // 128 KB

  prep_pack<<<dim3(96), dim3(256), 0, stream>>>(W1, W2, Wemb, W1P, W2P);
  mlp_graph<<<dim3(512), dim3(512), 0, stream>>>(
      h, last, Wemb, bemb, W1, b1, b2, W3, b3, W1P, W2P, d_out);
}

// Round 8
// 166.591 us; speedup vs baseline: 1.1504x; 1.1504x over previous
//
#include <hip/hip_runtime.h>

// Batch_Edge: B=512 graphs x 256 nodes; out1=tanh([h|emb[g]]@W1+b1);
// out2=tanh(out1@W2+b2); edges=out2@W3+b3 -> out[2*node+e].
// ebias trick: layer-1 K=128 (h@W1[:128]), emb folded into per-graph ebias.
// R7: 1 blk/graph, 4 waves, 64-row tiles: 66us, Occ 19%, no spill. Best.
// R8-R13 occupancy arc: every config with >8 waves/CU either spills
//   (64 acc + 4 waves/SIMD) or loses tile/barrier economics (R12 32-row,
//   R13 8-wave single-barrier-domain blocks: same 8 waves/CU as R7 but
//   103us -- independent blocks' phase overlap was the real resource).
// R14: attack R7's stalls directly, keep its proven shape (256 thr, grid
//   512, acc[4][4], lb(256,2), 2 blk/CU):
//   a) double-buffer LDS: smA (h/out2) + smB (out1) -> 4 barriers/tile
//      (was 7): epilogue writes no longer conflict with MFMA reads.
//   b) swapped-operand MFMA (W-frag as A, h-frag as B): lane's 4 acc vals
//      = 4 ADJACENT COLS of one row -> v_cvt_pk_bf16_f32 pairs + ds_write
//      _b64: 16 f2b + 16 b16-writes per epilogue -> 8 cvt_pk + 4 b64-writes.
//      Frag layouts A/B identical => W1P/W2P packing unchanged; out1/out2
//      stay row-major => downstream reads unchanged.
// ws: W1P 64K + W2P 128K = 196608 <= 262208 (R4-proven bound).

typedef __attribute__((ext_vector_type(8))) short s16x8;  // 8 bf16 = 4 VGPRs
typedef __attribute__((ext_vector_type(4))) float f32x4;

#define K2   256
#define KH   128
#define LDK  264    // row stride (elems): 528B rows, 16B-aligned

__device__ __forceinline__ float b2f(unsigned short u) {
  return __builtin_bit_cast(float, (unsigned int)u << 16);
}
__device__ __forceinline__ unsigned short f2b(float f) {
  unsigned int u = __builtin_bit_cast(unsigned int, f);
  u += 0x7fffu + ((u >> 16) & 1u);   // RNE
  return (unsigned short)(u >> 16);
}
// pack 2 f32 -> 2 bf16 in one u32 (RNE), single HW instr (no builtin).
__device__ __forceinline__ unsigned int cvt_pk_bf16(float lo, float hi) {
  unsigned int r;
  asm("v_cvt_pk_bf16_f32 %0, %1, %2" : "=v"(r) : "v"(lo), "v"(hi));
  return r;
}
// tanh via Pade(5/4)+clamp: max err ~1.1e-3 (< bf16 quantum), no NaN/ovf.
__device__ __forceinline__ float pade_tanh(float x) {
  float x2 = x * x;
  float x4 = x2 * x2;
  float num = x * (945.0f + 105.0f * x2 + x4);
  float den = __builtin_fmaf(15.0f, x4, __builtin_fmaf(420.0f, x2, 945.0f));
  float r = num * __builtin_amdgcn_rcpf(den);
  return __builtin_fmaxf(-1.0f, __builtin_fminf(1.0f, r));
}
// dtype probe: low u16 of each W_embed dword has bf16-plausible exponent iff
// storage is bf16 (values ~N(0,1/sqrt(128))).
__device__ __forceinline__ unsigned int probe_is16(const unsigned int* wraw,
                                                   int t) {
  unsigned int w = wraw[t];
  unsigned int e = (w >> 7) & 0xFFu;
  unsigned long long m = __ballot(e >= 96 && e < 128);
  return (__popcll(m) >= 32) ? 1u : 0u;
}

// ---- prep: frag-pack W1[:128] and W2 ----
// pack: D[(n>>4)*pk + (k>>3)*128 + (n&15)*8 + (k&7)]; frag load for
// (nblk,kchunk) is one contiguous 1KB wave read. (Verified R5/R6.)
__global__ __launch_bounds__(256) void prep_pack(
    const void* __restrict__ W1, const void* __restrict__ W2,
    const void* __restrict__ Wemb,
    unsigned short* __restrict__ W1P, unsigned short* __restrict__ W2P)
{
  __shared__ unsigned int flagLds;
  const int blk = blockIdx.x, t = threadIdx.x;
  if (t < 64) { unsigned int f = probe_is16((const unsigned int*)Wemb, t);
                if (t == 0) flagLds = f; }
  __syncthreads();
  const bool is16 = flagLds != 0u;

  const void* S; unsigned short* D; int k0, n0, pk;
  if (blk < 32) { S = W1; D = W1P; pk = 2048;                  // 128k x 256n
                  k0 = (blk & 3) * 32; n0 = (blk >> 2) * 32; }
  else { int b = blk - 32; S = W2; D = W2P; pk = 4096;         // 256k x 256n
         k0 = (b & 7) * 32; n0 = (b >> 3) * 32; }
  #pragma unroll
  for (int q = 0; q < 4; ++q) {
    int idx = t + 256 * q;                 // 32k x 32n, n fast (coalesced)
    int ln = idx & 31, lk = idx >> 5;
    int n = n0 + ln, k = k0 + lk;
    unsigned short v = is16
        ? ((const unsigned short*)S)[k * K2 + n]
        : f2b(((const float*)S)[k * K2 + n]);
    D[(n >> 4) * pk + (k >> 3) * 128 + (n & 15) * 8 + (k & 7)] = v;
  }
}

// ---- fused MLP: 1 block/graph; 4 tiles x 64 rows; 256 thr = 4 waves ------
__global__ __launch_bounds__(256, 2) void mlp_graph(
    const void* __restrict__ h,     const void* __restrict__ last,
    const void* __restrict__ Wemb,  const void* __restrict__ bemb,
    const void* __restrict__ W1,    const void* __restrict__ b1,
    const void* __restrict__ b2,
    const void* __restrict__ W3,    const void* __restrict__ b3,
    const unsigned short* __restrict__ W1P,
    const unsigned short* __restrict__ W2P,
    void* __restrict__ out)
{
  __shared__ __align__(16) unsigned short smA[64 * LDK];  // h, then out2
  __shared__ __align__(16) unsigned short smB[64 * LDK];  // out1
  __shared__ float embp[2][KH];                // embf K-half partials
  __shared__ float emb32[KH];                  // emb row, f32
  __shared__ float ebias[K2];                  // b1 + emb@W1[128:]
  __shared__ float b2s[K2];                    // b2 staged f32
  __shared__ float headp[4][64][2];
  __shared__ unsigned int flagLds;

  const int t    = threadIdx.x;
  const int lane = t & 63, w = t >> 6;         // wave owns cols [64w,64w+64)
  const int quad = lane >> 4, l16 = lane & 15;
  const int g    = blockIdx.x;                 // graph id

  if (t < 64) { unsigned int f = probe_is16((const unsigned int*)Wemb, t);
                if (t == 0) flagLds = f; }
  __syncthreads();
  const bool is16 = flagLds != 0u;

  // ---- embf partials: all 256 thr; col j=t&127, K-half=t>>7 ----
  {
    const int j = t & 127, half = t >> 7, k0 = half * 64;
    float a0 = 0.f, a1 = 0.f, a2 = 0.f, a3 = 0.f;
    if (is16) {
      const unsigned short* lp = (const unsigned short*)last + g * KH;
      const unsigned short* wp = (const unsigned short*)Wemb;
      #pragma unroll 4
      for (int k = k0; k < k0 + 64; k += 4) {
        a0 += b2f(lp[k])     * b2f(wp[k * KH + j]);
        a1 += b2f(lp[k + 1]) * b2f(wp[(k + 1) * KH + j]);
        a2 += b2f(lp[k + 2]) * b2f(wp[(k + 2) * KH + j]);
        a3 += b2f(lp[k + 3]) * b2f(wp[(k + 3) * KH + j]);
      }
    } else {
      const float* lp = (const float*)last + g * KH;
      const float* wp = (const float*)Wemb;
      #pragma unroll 4
      for (int k = k0; k < k0 + 64; k += 4) {
        a0 += lp[k]     * wp[k * KH + j];
        a1 += lp[k + 1] * wp[(k + 1) * KH + j];
        a2 += lp[k + 2] * wp[(k + 2) * KH + j];
        a3 += lp[k + 3] * wp[(k + 3) * KH + j];
      }
    }
    embp[half][j] = (a0 + a1) + (a2 + a3);
  }

  // ---- persistent per-wave registers: head W3 frags ----
  s16x8 bh[2];                                 // head B: wave w covers k 64w..
  #pragma unroll
  for (int s = 0; s < 2; ++s) {
    int kk = 2 * w + s;
    #pragma unroll
    for (int j = 0; j < 8; ++j) {
      int kidx = (kk * 32 + quad * 8 + j) * 2 + (l16 & 1);
      bh[s][j] = is16 ? (short)((const unsigned short*)W3)[kidx]
                      : (short)f2b(((const float*)W3)[kidx]);
    }
  }
  // stage b2 (f32) to LDS: epilogue needs cols quad*4+rg (broadcast reads)
  if (t < K2)
    b2s[t] = is16 ? b2f(((const unsigned short*)b2)[t])
                  : ((const float*)b2)[t];
  float b3e = 0.f;
  if (t < 128)
    b3e = is16 ? b2f(((const unsigned short*)b3)[t & 1])
               : ((const float*)b3)[t & 1];
  __syncthreads();                             // embp ready

  if (t < KH) {
    float e = is16 ? b2f(((const unsigned short*)bemb)[t])
                   : ((const float*)bemb)[t];
    emb32[t] = e + embp[0][t] + embp[1][t];
  }
  __syncthreads();                             // emb32 ready

  // ---- ebias[col=t] = b1[col] + sum_k emb32[k]*W1[128+k][col] (f32 GEMV) --
  // L2-hot raw W1 rows 128:255, coalesced over t (proven R11).
  {
    float s = is16 ? b2f(((const unsigned short*)b1)[t])
                   : ((const float*)b1)[t];
    if (is16) {
      const unsigned short* wp = (const unsigned short*)W1
                                 + (size_t)KH * K2 + t;
      #pragma unroll 4
      for (int k = 0; k < KH; ++k)
        s = __builtin_fmaf(emb32[k], b2f(wp[(size_t)k * K2]), s);
    } else {
      const float* wp = (const float*)W1 + (size_t)KH * K2 + t;
      #pragma unroll 4
      for (int k = 0; k < KH; ++k)
        s = __builtin_fmaf(emb32[k], wp[(size_t)k * K2], s);
    }
    ebias[t] = s;
  }

  // ---- prefetch tile 0 h into registers ----
  uint4 hreg[4];
  const int pr = t >> 4, pc = t & 15;          // 64 rows x 16 chunks / 256 thr
  auto load_tile = [&](int tile) {
    int rbase = g * 256 + tile * 64;
    if (is16) {
      const uint4* hp = (const uint4*)h;
      #pragma unroll
      for (int i = 0; i < 4; ++i)
        hreg[i] = hp[(size_t)(rbase + pr + 16 * i) * 16 + pc];
    } else {
      const float4* hf = (const float4*)h;
      #pragma unroll
      for (int i = 0; i < 4; ++i) {
        float4 va = hf[(size_t)(rbase + pr + 16 * i) * 32 + pc * 2];
        float4 vb = hf[(size_t)(rbase + pr + 16 * i) * 32 + pc * 2 + 1];
        ushort4 ua, ub;
        ua.x = f2b(va.x); ua.y = f2b(va.y); ua.z = f2b(va.z); ua.w = f2b(va.w);
        ub.x = f2b(vb.x); ub.y = f2b(vb.y); ub.z = f2b(vb.z); ub.w = f2b(vb.w);
        hreg[i] = make_uint4(
            (unsigned)ua.x | ((unsigned)ua.y << 16),
            (unsigned)ua.z | ((unsigned)ua.w << 16),
            (unsigned)ub.x | ((unsigned)ub.y << 16),
            (unsigned)ub.z | ((unsigned)ub.w << 16));
      }
    }
  };
  load_tile(0);

  f32x4 acc[4][4];
  for (int tile = 0; tile < 4; ++tile) {
    const int base = g * 256 + tile * 64;
    // A free: prev tile's head reads completed at bar3 (or preamble sync)
    #pragma unroll
    for (int i = 0; i < 4; ++i)
      *(uint4*)&smA[(pr + 16 * i) * LDK + pc * 8] = hreg[i];
    if (tile < 3) load_tile(tile + 1);         // overlap HBM with compute
    __syncthreads();                           // bar0: h visible (+ebias t0)

    // ---- layer 1: K=128, swapped operands (W-frag=A, h-frag=B) ----
    // D: row(quad*4+rg)=col n, col(l16)=row r -> lane holds 4 adjacent cols.
    #pragma unroll
    for (int i = 0; i < 4; ++i)
      #pragma unroll
      for (int c = 0; c < 4; ++c) acc[i][c] = f32x4{0.f, 0.f, 0.f, 0.f};
    #pragma unroll
    for (int kk = 0; kk < 4; ++kk) {
      s16x8 a[4], b[4];
      #pragma unroll
      for (int i = 0; i < 4; ++i)
        a[i] = *(const s16x8*)&smA[(i * 16 + l16) * LDK + kk * 32 + quad * 8];
      #pragma unroll
      for (int c = 0; c < 4; ++c)
        b[c] = *(const s16x8*)&W1P[(w * 4 + c) * 2048
                                   + (kk * 4 + quad) * 128 + l16 * 8];
      #pragma unroll
      for (int i = 0; i < 4; ++i)
        #pragma unroll
        for (int c = 0; c < 4; ++c)
          acc[i][c] = __builtin_amdgcn_mfma_f32_16x16x32_bf16(
              b[c], a[i], acc[i][c], 0, 0, 0);
    }
    // out1 -> smB: no barrier needed (different buffer than MFMA reads)
    #pragma unroll
    for (int c = 0; c < 4; ++c) {
      const int n0 = w * 64 + c * 16 + quad * 4;
      const float e0 = ebias[n0],     e1 = ebias[n0 + 1];
      const float e2 = ebias[n0 + 2], e3 = ebias[n0 + 3];
      #pragma unroll
      for (int i = 0; i < 4; ++i) {
        unsigned p0 = cvt_pk_bf16(pade_tanh(acc[i][c][0] + e0),
                                  pade_tanh(acc[i][c][1] + e1));
        unsigned p1 = cvt_pk_bf16(pade_tanh(acc[i][c][2] + e2),
                                  pade_tanh(acc[i][c][3] + e3));
        *(uint2*)&smB[(i * 16 + l16) * LDK + n0] = make_uint2(p0, p1);
      }
    }
    __syncthreads();                           // bar1: out1 visible

    // ---- layer 2: K=256, swapped operands, B-frag from smB ----
    #pragma unroll
    for (int i = 0; i < 4; ++i)
      #pragma unroll
      for (int c = 0; c < 4; ++c) acc[i][c] = f32x4{0.f, 0.f, 0.f, 0.f};
    #pragma unroll 2
    for (int kk = 0; kk < 8; ++kk) {
      s16x8 a[4], b[4];
      #pragma unroll
      for (int i = 0; i < 4; ++i)
        a[i] = *(const s16x8*)&smB[(i * 16 + l16) * LDK + kk * 32 + quad * 8];
      #pragma unroll
      for (int c = 0; c < 4; ++c)
        b[c] = *(const s16x8*)&W2P[(w * 4 + c) * 4096
                                   + (kk * 4 + quad) * 128 + l16 * 8];
      #pragma unroll
      for (int i = 0; i < 4; ++i)
        #pragma unroll
        for (int c = 0; c < 4; ++c)
          acc[i][c] = __builtin_amdgcn_mfma_f32_16x16x32_bf16(
              b[c], a[i], acc[i][c], 0, 0, 0);
    }
    // out2 -> smA (h dead; all smA reads finished before bar1)
    #pragma unroll
    for (int c = 0; c < 4; ++c) {
      const int n0 = w * 64 + c * 16 + quad * 4;
      const float e0 = b2s[n0],     e1 = b2s[n0 + 1];
      const float e2 = b2s[n0 + 2], e3 = b2s[n0 + 3];
      #pragma unroll
      for (int i = 0; i < 4; ++i) {
        unsigned p0 = cvt_pk_bf16(pade_tanh(acc[i][c][0] + e0),
                                  pade_tanh(acc[i][c][1] + e1));
        unsigned p1 = cvt_pk_bf16(pade_tanh(acc[i][c][2] + e2),
                                  pade_tanh(acc[i][c][3] + e3));
        *(uint2*)&smA[(i * 16 + l16) * LDK + n0] = make_uint2(p0, p1);
      }
    }
    __syncthreads();                           // bar2: out2 visible

    // ---- head via MFMA (normal orientation): wave w covers k 64w..64w+64 --
    // accumulates into acc[i][0] (dead): forced register reuse.
    {
      #pragma unroll
      for (int i = 0; i < 4; ++i) acc[i][0] = f32x4{0.f, 0.f, 0.f, 0.f};
      #pragma unroll
      for (int s = 0; s < 2; ++s) {
        int kk = 2 * w + s;
        #pragma unroll
        for (int i = 0; i < 4; ++i) {
          s16x8 a = *(const s16x8*)&smA[(i * 16 + l16) * LDK
                                        + kk * 32 + quad * 8];
          acc[i][0] = __builtin_amdgcn_mfma_f32_16x16x32_bf16(
              a, bh[s], acc[i][0], 0, 0, 0);
        }
      }
      if (l16 < 2) {
        #pragma unroll
        for (int i = 0; i < 4; ++i)
          #pragma unroll
          for (int rg = 0; rg < 4; ++rg)
            headp[w][i * 16 + quad * 4 + rg][l16] = acc[i][0][rg];
      }
    }
    __syncthreads();                           // bar3: headp visible, A free
    if (t < 128) {
      const int r = t >> 1, e = t & 1;
      float s = b3e + headp[0][r][e] + headp[1][r][e]
                    + headp[2][r][e] + headp[3][r][e];
      size_t idx = (size_t)(base + r) * 2 + e;
      if (is16) ((unsigned short*)out)[idx] = f2b(s);
      else      ((float*)out)[idx] = s;
    }
  }
}

extern "C" void kernel_launch(void* const* d_in, const int* in_sizes, int n_in,
                              void* d_out, int out_size, void* d_ws, size_t ws_size,
                              hipStream_t stream) {
  (void)in_sizes; (void)n_in; (void)out_size; (void)ws_size;
  const void* last = d_in[0];
  const void* h    = d_in[1];
  const void* Wemb = d_in[2];
  const void* bemb = d_in[3];
  const void* W1   = d_in[4];
  const void* b1   = d_in[5];
  const void* W2   = d_in[6];
  const void* b2   = d_in[7];
  const void* W3   = d_in[8];
  const void* b3   = d_in[9];
  // d_in[10]=segment_ids, d_in[11]=max_nodes: regular structure, unused.

  // ws usage: 196608 B <= 262208 (R4-proven bound).
  char* ws = (char*)d_ws;
  unsigned short* W1P   = (unsigned short*)(ws);            // 64 KB
  unsigned short* W2P   = (unsigned short*)(ws + 65536);    // 128 KB

  prep_pack<<<dim3(96), dim3(256), 0, stream>>>(W1, W2, Wemb, W1P, W2P);
  mlp_graph<<<dim3(512), dim3(256), 0, stream>>>(
      h, last, Wemb, bemb, W1, b1, b2, W3, b3, W1P, W2P, d_out);
}

// Round 9
// 165.420 us; speedup vs baseline: 1.1585x; 1.0071x over previous
//
#include <hip/hip_runtime.h>

// Batch_Edge: B=512 graphs x 256 nodes; out1=tanh([h|emb[g]]@W1+b1);
// out2=tanh(out1@W2+b2); edges=out2@W3+b3 -> out[2*node+e].
// ebias trick: layer-1 K=128 (h@W1[:128]), emb folded into per-graph ebias.
// R7 (best): 1 blk/graph, 4 waves, 64-row tiles, w1f[16] resident,
//   7 bar/tile: 66-73us, Occ 19%, no spill. ~28us stall (VALU 29us busy,
//   MFMA 10us, rest barrier drains at 2 blk/CU).
// R8-R13: occupancy arc dead (spill or tile-economics loss). R14: packed
//   cvt_pk epilogue + W1P streaming + smB dbuf -> 95us. Post-mortem: same
//   VALU/MFMA busy TIME as R7, +28us stall. cvt_pk inline-asm is a known
//   pitfall (m240, -37%); W1P streaming re-added latency chains R7's
//   resident w1f avoided; strided uint2 writes +57% bank conflicts. The
//   smB dbuf (7->4 barriers) was never isolated.
// R15: R7 EXACTLY + two proven deltas: (a) smB double-buffer -> 4 bar/tile;
//   (b) R11's f32 GEMV ebias (no W1loP/prep3, -16 AGPR, off hot loop).
//   Scalar f2b epilogue, w1f resident, hreg prefetch, acc[i][0] head reuse.
//   LDS ~72KB, 2 blk/CU (R14-confirmed resident).
// ws: W1P 64K + W2P 128K = 196608 <= 262208 (R4-proven bound).

typedef __attribute__((ext_vector_type(8))) short s16x8;  // 8 bf16 = 4 VGPRs
typedef __attribute__((ext_vector_type(4))) float f32x4;

#define K2   256
#define KH   128
#define LDK  264    // row stride (elems): 528B rows, 16B-aligned

__device__ __forceinline__ float b2f(unsigned short u) {
  return __builtin_bit_cast(float, (unsigned int)u << 16);
}
__device__ __forceinline__ unsigned short f2b(float f) {
  unsigned int u = __builtin_bit_cast(unsigned int, f);
  u += 0x7fffu + ((u >> 16) & 1u);   // RNE
  return (unsigned short)(u >> 16);
}
// tanh via Pade(5/4)+clamp: max err ~1.1e-3 (< bf16 quantum), no NaN/ovf.
__device__ __forceinline__ float pade_tanh(float x) {
  float x2 = x * x;
  float x4 = x2 * x2;
  float num = x * (945.0f + 105.0f * x2 + x4);
  float den = __builtin_fmaf(15.0f, x4, __builtin_fmaf(420.0f, x2, 945.0f));
  float r = num * __builtin_amdgcn_rcpf(den);
  return __builtin_fmaxf(-1.0f, __builtin_fminf(1.0f, r));
}
// dtype probe: low u16 of each W_embed dword has bf16-plausible exponent iff
// storage is bf16 (values ~N(0,1/sqrt(128))).
__device__ __forceinline__ unsigned int probe_is16(const unsigned int* wraw,
                                                   int t) {
  unsigned int w = wraw[t];
  unsigned int e = (w >> 7) & 0xFFu;
  unsigned long long m = __ballot(e >= 96 && e < 128);
  return (__popcll(m) >= 32) ? 1u : 0u;
}

// ---- prep: frag-pack W1[:128] and W2 ----
// pack: D[(n>>4)*pk + (k>>3)*128 + (n&15)*8 + (k&7)]; B-frag load for
// (nblk,kchunk) is one contiguous 1KB wave read. (Verified R5/R6.)
__global__ __launch_bounds__(256) void prep_pack(
    const void* __restrict__ W1, const void* __restrict__ W2,
    const void* __restrict__ Wemb,
    unsigned short* __restrict__ W1P, unsigned short* __restrict__ W2P)
{
  __shared__ unsigned int flagLds;
  const int blk = blockIdx.x, t = threadIdx.x;
  if (t < 64) { unsigned int f = probe_is16((const unsigned int*)Wemb, t);
                if (t == 0) flagLds = f; }
  __syncthreads();
  const bool is16 = flagLds != 0u;

  const void* S; unsigned short* D; int k0, n0, pk;
  if (blk < 32) { S = W1; D = W1P; pk = 2048;                  // 128k x 256n
                  k0 = (blk & 3) * 32; n0 = (blk >> 2) * 32; }
  else { int b = blk - 32; S = W2; D = W2P; pk = 4096;         // 256k x 256n
         k0 = (b & 7) * 32; n0 = (b >> 3) * 32; }
  #pragma unroll
  for (int q = 0; q < 4; ++q) {
    int idx = t + 256 * q;                 // 32k x 32n, n fast (coalesced)
    int ln = idx & 31, lk = idx >> 5;
    int n = n0 + ln, k = k0 + lk;
    unsigned short v = is16
        ? ((const unsigned short*)S)[k * K2 + n]
        : f2b(((const float*)S)[k * K2 + n]);
    D[(n >> 4) * pk + (k >> 3) * 128 + (n & 15) * 8 + (k & 7)] = v;
  }
}

// ---- fused MLP: 1 block per graph; 4 tiles x 64 rows; 256 thr = 4 waves --
__global__ __launch_bounds__(256, 2) void mlp_graph(
    const void* __restrict__ h,     const void* __restrict__ last,
    const void* __restrict__ Wemb,  const void* __restrict__ bemb,
    const void* __restrict__ W1,    const void* __restrict__ b1,
    const void* __restrict__ b2,
    const void* __restrict__ W3,    const void* __restrict__ b3,
    const unsigned short* __restrict__ W1P,
    const unsigned short* __restrict__ W2P,
    void* __restrict__ out)
{
  __shared__ __align__(16) unsigned short smA[64 * LDK];  // h, then out2
  __shared__ __align__(16) unsigned short smB[64 * LDK];  // out1
  __shared__ float embp[2][KH];                // embf K-half partials
  __shared__ float emb32[KH];                  // emb row, f32
  __shared__ float ebias[K2];                  // b1 + emb@W1[128:]
  __shared__ float headp[4][64][2];
  __shared__ unsigned int flagLds;

  const int t    = threadIdx.x;
  const int lane = t & 63, w = t >> 6;         // wave owns cols [64w,64w+64)
  const int quad = lane >> 4, l16 = lane & 15;
  const int g    = blockIdx.x;                 // graph id

  if (t < 64) { unsigned int f = probe_is16((const unsigned int*)Wemb, t);
                if (t == 0) flagLds = f; }
  __syncthreads();
  const bool is16 = flagLds != 0u;

  // ---- embf partials: all 256 thr; col j=t&127, K-half=t>>7 ----
  {
    const int j = t & 127, half = t >> 7, k0 = half * 64;
    float a0 = 0.f, a1 = 0.f, a2 = 0.f, a3 = 0.f;
    if (is16) {
      const unsigned short* lp = (const unsigned short*)last + g * KH;
      const unsigned short* wp = (const unsigned short*)Wemb;
      #pragma unroll 4
      for (int k = k0; k < k0 + 64; k += 4) {
        a0 += b2f(lp[k])     * b2f(wp[k * KH + j]);
        a1 += b2f(lp[k + 1]) * b2f(wp[(k + 1) * KH + j]);
        a2 += b2f(lp[k + 2]) * b2f(wp[(k + 2) * KH + j]);
        a3 += b2f(lp[k + 3]) * b2f(wp[(k + 3) * KH + j]);
      }
    } else {
      const float* lp = (const float*)last + g * KH;
      const float* wp = (const float*)Wemb;
      #pragma unroll 4
      for (int k = k0; k < k0 + 64; k += 4) {
        a0 += lp[k]     * wp[k * KH + j];
        a1 += lp[k + 1] * wp[(k + 1) * KH + j];
        a2 += lp[k + 2] * wp[(k + 2) * KH + j];
        a3 += lp[k + 3] * wp[(k + 3) * KH + j];
      }
    }
    embp[half][j] = (a0 + a1) + (a2 + a3);
  }

  // ---- persistent per-block registers: W1 frags, head W3 frags, biases ----
  s16x8 w1f[16];                               // 64 VGPRs, reused 4 tiles
  #pragma unroll
  for (int kk = 0; kk < 4; ++kk)
    #pragma unroll
    for (int c = 0; c < 4; ++c)
      w1f[kk * 4 + c] = *(const s16x8*)&W1P[(w * 4 + c) * 2048
                                            + (kk * 4 + quad) * 128 + l16 * 8];
  s16x8 bh[2];                                 // head B: wave w covers k 64w..
  #pragma unroll
  for (int s = 0; s < 2; ++s) {
    int kk = 2 * w + s;
    #pragma unroll
    for (int j = 0; j < 8; ++j) {
      int kidx = (kk * 32 + quad * 8 + j) * 2 + (l16 & 1);
      bh[s][j] = is16 ? (short)((const unsigned short*)W3)[kidx]
                      : (short)f2b(((const float*)W3)[kidx]);
    }
  }
  float b2v[4];
  #pragma unroll
  for (int c = 0; c < 4; ++c) {
    int col = w * 64 + c * 16 + l16;
    b2v[c] = is16 ? b2f(((const unsigned short*)b2)[col])
                  : ((const float*)b2)[col];
  }
  float b3e = 0.f;
  if (t < 128)
    b3e = is16 ? b2f(((const unsigned short*)b3)[t & 1])
               : ((const float*)b3)[t & 1];
  __syncthreads();                             // embp ready

  if (t < KH) {
    float e = is16 ? b2f(((const unsigned short*)bemb)[t])
                   : ((const float*)bemb)[t];
    emb32[t] = e + embp[0][t] + embp[1][t];
  }
  __syncthreads();                             // emb32 ready

  // ---- ebias[col=t] = b1[col] + sum_k emb32[k]*W1[128+k][col] (f32 GEMV) --
  // L2-hot raw W1 rows 128:255, coalesced over t (proven R11). Visibility
  // to epi1 readers is covered by bar0 inside the tile loop.
  {
    float s = is16 ? b2f(((const unsigned short*)b1)[t])
                   : ((const float*)b1)[t];
    if (is16) {
      const unsigned short* wp = (const unsigned short*)W1
                                 + (size_t)KH * K2 + t;
      #pragma unroll 4
      for (int k = 0; k < KH; ++k)
        s = __builtin_fmaf(emb32[k], b2f(wp[(size_t)k * K2]), s);
    } else {
      const float* wp = (const float*)W1 + (size_t)KH * K2 + t;
      #pragma unroll 4
      for (int k = 0; k < KH; ++k)
        s = __builtin_fmaf(emb32[k], wp[(size_t)k * K2], s);
    }
    ebias[t] = s;
  }

  // ---- prefetch tile 0 h into registers ----
  uint4 hreg[4];
  const int pr = t >> 4, pc = t & 15;          // 64 rows x 16 chunks / 256 thr
  auto load_tile = [&](int tile) {
    int rbase = g * 256 + tile * 64;
    if (is16) {
      const uint4* hp = (const uint4*)h;
      #pragma unroll
      for (int i = 0; i < 4; ++i)
        hreg[i] = hp[(size_t)(rbase + pr + 16 * i) * 16 + pc];
    } else {
      const float4* hf = (const float4*)h;
      #pragma unroll
      for (int i = 0; i < 4; ++i) {
        float4 va = hf[(size_t)(rbase + pr + 16 * i) * 32 + pc * 2];
        float4 vb = hf[(size_t)(rbase + pr + 16 * i) * 32 + pc * 2 + 1];
        ushort4 ua, ub;
        ua.x = f2b(va.x); ua.y = f2b(va.y); ua.z = f2b(va.z); ua.w = f2b(va.w);
        ub.x = f2b(vb.x); ub.y = f2b(vb.y); ub.z = f2b(vb.z); ub.w = f2b(vb.w);
        hreg[i] = make_uint4(
            (unsigned)ua.x | ((unsigned)ua.y << 16),
            (unsigned)ua.z | ((unsigned)ua.w << 16),
            (unsigned)ub.x | ((unsigned)ub.y << 16),
            (unsigned)ub.z | ((unsigned)ub.w << 16));
      }
    }
  };
  load_tile(0);

  f32x4 acc[4][4];
  for (int tile = 0; tile < 4; ++tile) {
    const int base = g * 256 + tile * 64;
    // smA free here: prev tile's head reads drained at bar3 (preamble for t0)
    #pragma unroll
    for (int i = 0; i < 4; ++i)
      *(uint4*)&smA[(pr + 16 * i) * LDK + pc * 8] = hreg[i];
    if (tile < 3) load_tile(tile + 1);         // overlap HBM with compute
    __syncthreads();                           // bar0: h (and ebias) visible

    // ---- layer 1: K=128, B from resident w1f registers (R7) ----
    #pragma unroll
    for (int i = 0; i < 4; ++i)
      #pragma unroll
      for (int c = 0; c < 4; ++c) acc[i][c] = f32x4{0.f, 0.f, 0.f, 0.f};
    #pragma unroll
    for (int kk = 0; kk < 4; ++kk) {
      s16x8 a[4];
      #pragma unroll
      for (int i = 0; i < 4; ++i)
        a[i] = *(const s16x8*)&smA[(i * 16 + l16) * LDK + kk * 32 + quad * 8];
      #pragma unroll
      for (int i = 0; i < 4; ++i)
        #pragma unroll
        for (int c = 0; c < 4; ++c)
          acc[i][c] = __builtin_amdgcn_mfma_f32_16x16x32_bf16(
              a[i], w1f[kk * 4 + c], acc[i][c], 0, 0, 0);
    }
    // out1 -> smB: no barrier needed (distinct buffer from smA being read;
    // smB's prior readers finished before prev bar2). Scalar f2b, column-
    // contiguous writes (R7 pattern -- conflict-light).
    #pragma unroll
    for (int c = 0; c < 4; ++c) {
      int col = w * 64 + c * 16 + l16;
      float eb = ebias[col];
      #pragma unroll
      for (int i = 0; i < 4; ++i)
        #pragma unroll
        for (int rg = 0; rg < 4; ++rg)         // D: row=quad*4+rg, col=l16
          smB[(i * 16 + quad * 4 + rg) * LDK + col] =
              f2b(pade_tanh(acc[i][c][rg] + eb));
    }
    __syncthreads();                           // bar1: out1 visible

    // ---- layer 2: K=256, A from smB, B from W2P (L2-hot) ----
    #pragma unroll
    for (int i = 0; i < 4; ++i)
      #pragma unroll
      for (int c = 0; c < 4; ++c) acc[i][c] = f32x4{0.f, 0.f, 0.f, 0.f};
    #pragma unroll 2
    for (int kk = 0; kk < 8; ++kk) {
      s16x8 a[4], b[4];
      #pragma unroll
      for (int i = 0; i < 4; ++i)
        a[i] = *(const s16x8*)&smB[(i * 16 + l16) * LDK + kk * 32 + quad * 8];
      #pragma unroll
      for (int c = 0; c < 4; ++c)
        b[c] = *(const s16x8*)&W2P[(w * 4 + c) * 4096
                                   + (kk * 4 + quad) * 128 + l16 * 8];
      #pragma unroll
      for (int i = 0; i < 4; ++i)
        #pragma unroll
        for (int c = 0; c < 4; ++c)
          acc[i][c] = __builtin_amdgcn_mfma_f32_16x16x32_bf16(
              a[i], b[c], acc[i][c], 0, 0, 0);
    }
    // out2 -> smA: smA reads (L1) drained before bar1; h is dead.
    #pragma unroll
    for (int c = 0; c < 4; ++c) {
      int col = w * 64 + c * 16 + l16;
      #pragma unroll
      for (int i = 0; i < 4; ++i)
        #pragma unroll
        for (int rg = 0; rg < 4; ++rg)
          smA[(i * 16 + quad * 4 + rg) * LDK + col] =
              f2b(pade_tanh(acc[i][c][rg] + b2v[c]));
    }
    __syncthreads();                           // bar2: out2 visible

    // ---- head via MFMA: wave w covers k in [64w,64w+64) ----
    // accumulates into acc[i][0] (dead after L2 epilogue): forced reuse.
    {
      #pragma unroll
      for (int i = 0; i < 4; ++i) acc[i][0] = f32x4{0.f, 0.f, 0.f, 0.f};
      #pragma unroll
      for (int s = 0; s < 2; ++s) {
        int kk = 2 * w + s;
        #pragma unroll
        for (int i = 0; i < 4; ++i) {
          s16x8 a = *(const s16x8*)&smA[(i * 16 + l16) * LDK
                                        + kk * 32 + quad * 8];
          acc[i][0] = __builtin_amdgcn_mfma_f32_16x16x32_bf16(
              a, bh[s], acc[i][0], 0, 0, 0);
        }
      }
      if (l16 < 2) {
        #pragma unroll
        for (int i = 0; i < 4; ++i)
          #pragma unroll
          for (int rg = 0; rg < 4; ++rg)
            headp[w][i * 16 + quad * 4 + rg][l16] = acc[i][0][rg];
      }
    }
    __syncthreads();                           // bar3: headp visible, smA free
    if (t < 128) {
      const int r = t >> 1, e = t & 1;
      float s = b3e + headp[0][r][e] + headp[1][r][e]
                    + headp[2][r][e] + headp[3][r][e];
      size_t idx = (size_t)(base + r) * 2 + e;
      if (is16) ((unsigned short*)out)[idx] = f2b(s);
      else      ((float*)out)[idx] = s;
    }
  }
}

extern "C" void kernel_launch(void* const* d_in, const int* in_sizes, int n_in,
                              void* d_out, int out_size, void* d_ws, size_t ws_size,
                              hipStream_t stream) {
  (void)in_sizes; (void)n_in; (void)out_size; (void)ws_size;
  const void* last = d_in[0];
  const void* h    = d_in[1];
  const void* Wemb = d_in[2];
  const void* bemb = d_in[3];
  const void* W1   = d_in[4];
  const void* b1   = d_in[5];
  const void* W2   = d_in[6];
  const void* b2   = d_in[7];
  const void* W3   = d_in[8];
  const void* b3   = d_in[9];
  // d_in[10]=segment_ids, d_in[11]=max_nodes: regular structure, unused.

  // ws usage: 196608 B <= 262208 (R4-proven bound).
  char* ws = (char*)d_ws;
  unsigned short* W1P   = (unsigned short*)(ws);            // 64 KB
  unsigned short* W2P   = (unsigned short*)(ws + 65536);    // 128 KB

  prep_pack<<<dim3(96), dim3(256), 0, stream>>>(W1, W2, Wemb, W1P, W2P);
  mlp_graph<<<dim3(512), dim3(256), 0, stream>>>(
      h, last, Wemb, bemb, W1, b1, b2, W3, b3, W1P, W2P, d_out);
}